// Round 3
// baseline (109.626 us; speedup 1.0000x reference)
//
#include <hip/hip_runtime.h>

// DelayedXOR SH-SNN forward. One thread per independent (b,h) chain
// (s_g.reshape(B,H) maps (g,j)->h=g*16+j one-to-one; no cross-neuron coupling).
//
// R2 -> R3: R2's double-buffer was defeated by the register allocator
// (VGPR=52: default occupancy target ~8 waves/EU caps budget at 64, so loads
// get sunk onto the serial critical path; counters showed ~93 of 122
// cyc/step was vmcnt stall). Fix:
//   1. __launch_bounds__(64, 1): 1 wave/EU occupancy target -> ~256 VGPR
//      budget. (Only 512 waves exist for 1024 SIMDs; occupancy can't exceed
//      1 wave/SIMD regardless, so the hint is free.)
//   2. Prefetch distance 2 (3 rotating 16-step tiles, explicit 3-stage
//      rotation, no copies): first-touch loads are cold HBM (~900 cyc);
//      one tile of compute (~450 cyc) only covers half of that.
//
// Correctness: bit-exact fp32 vs numpy reference (absmax 0.0 in R1, R2).
// - fp contract OFF everywhere (no fma fusion)
// - exact expression order ((ag*v + omg*gi) - sf)
// - spike(v-1) == (v > 1.0f) exactly in fp32
// - (1-alpha)*integ as sf*oms: exact since sf in {0,1}
// - sigmoid in double, rounded once to fp32

constexpr int BATCH = 1024;
constexpr int T     = 1024;
constexpr int H     = 32;
// decision_start = max(T - T/4, T/2) = 768 -> tile 48 of 64 (16 steps/tile)
constexpr int NTILE    = 64;
constexpr int ACC_TILE = 48;

struct XT { float4 q0, q1, q2, q3, q4, q5, q6, q7; };  // 16 timesteps

__device__ __forceinline__ XT load_tile(const float4* __restrict__ p, int tile)
{
    int i = (tile > NTILE - 1 ? NTILE - 1 : tile) * 8;  // clamp: tail re-loads t63
    XT t;
    t.q0 = p[i+0]; t.q1 = p[i+1]; t.q2 = p[i+2]; t.q3 = p[i+3];
    t.q4 = p[i+4]; t.q5 = p[i+5]; t.q6 = p[i+6]; t.q7 = p[i+7];
    return t;
}

template <bool ACC>
__device__ __forceinline__ void step(float x0, float x1,
                                     float w0, float w1,
                                     float ag, float omg,
                                     float as, float oms,
                                     float& v, float& sf,
                                     float& V, float& Sf,
                                     float& acc)
{
#pragma clang fp contract(off)
    float m0 = x0 * w0;          // state-independent: fills latency slots
    float m1 = x1 * w1;
    float gi = m0 + m1;
    float t2 = omg * gi;
    float t1 = ag * v;           // serial core: mul -> add -> sub
    float u  = t1 + t2;
    v = u - sf;
    sf = (v > 1.0f) ? 1.0f : 0.0f;
    float a2 = sf * oms;         // exact for sf in {0,1}
    float a1 = as * V;
    float a3 = a1 + a2;
    V = a3 - Sf;
    Sf = (V > 1.0f) ? 1.0f : 0.0f;
    if (ACC) acc += Sf;
}

template <bool ACC>
__device__ __forceinline__ void tile16(const XT& t,
                                       float w0, float w1,
                                       float ag, float omg,
                                       float as, float oms,
                                       float& v, float& sf,
                                       float& V, float& Sf,
                                       float& acc)
{
#define STEP2(Q) \
    step<ACC>(Q.x, Q.y, w0, w1, ag, omg, as, oms, v, sf, V, Sf, acc); \
    step<ACC>(Q.z, Q.w, w0, w1, ag, omg, as, oms, v, sf, V, Sf, acc);
    STEP2(t.q0) STEP2(t.q1) STEP2(t.q2) STEP2(t.q3)
    STEP2(t.q4) STEP2(t.q5) STEP2(t.q6) STEP2(t.q7)
#undef STEP2
}

__global__ __launch_bounds__(64, 1) void snn_fwd(
    const float* __restrict__ x,       // [B, T, 2]
    const float* __restrict__ Wg,      // [2, 16, 2] == [h][2]
    const float* __restrict__ tau_m,   // [2, 16] == [h]
    const float* __restrict__ soma,    // [32]
    const float* __restrict__ W_out,   // [1, 32]
    const float* __restrict__ b_out,   // [1]
    float* __restrict__ out)           // [B, 1]
{
#pragma clang fp contract(off)
    const int gtid = blockIdx.x * blockDim.x + threadIdx.x;
    const int h = gtid & (H - 1);
    const int b = gtid >> 5;
    if (b >= BATCH) return;

    const float w0 = Wg[2*h + 0];
    const float w1 = Wg[2*h + 1];
    const float ag  = (float)(1.0 / (1.0 + exp(-(double)tau_m[h])));
    const float omg = 1.0f - ag;
    const float as  = (float)(1.0 / (1.0 + exp(-(double)soma[h])));
    const float oms = 1.0f - as;

    const float4* __restrict__ xrow = (const float4*)(x + (size_t)b * (2 * T));

    float v = 0.f, sf = 0.f, V = 0.f, Sf = 0.f, acc = 0.f;

    // 3-buffer pipeline, prefetch distance 2. Tile k lives in buffer k%3.
    XT A = load_tile(xrow, 0);   // buf 0 <- tile 0
    XT B = load_tile(xrow, 1);   // buf 1 <- tile 1
    XT C;

#define GROUP(KBASE, ACCFLAG)                                                 \
    C = load_tile(xrow, (KBASE) + 2);                                         \
    tile16<ACCFLAG>(A, w0, w1, ag, omg, as, oms, v, sf, V, Sf, acc);          \
    A = load_tile(xrow, (KBASE) + 3);                                         \
    tile16<ACCFLAG>(B, w0, w1, ag, omg, as, oms, v, sf, V, Sf, acc);          \
    B = load_tile(xrow, (KBASE) + 4);                                         \
    tile16<ACCFLAG>(C, w0, w1, ag, omg, as, oms, v, sf, V, Sf, acc);

    // phase 1: tiles 0..47 (16 groups of 3), no accumulation
    for (int k = 0; k < ACC_TILE; k += 3) {
        GROUP(k, false)
    }
    // phase 2: tiles 48..62 (5 groups of 3), accumulate S
    for (int k = ACC_TILE; k < NTILE - 1; k += 3) {
        GROUP(k, true)
    }
    // tile 63 sits in buffer 63%3 == 0 == A
    tile16<true>(A, w0, w1, ag, omg, as, oms, v, sf, V, Sf, acc);
#undef GROUP

    // out[b] = sum_h acc[h] * W_out[h] + b_out. Lanes 0-31 hold batch b_even,
    // lanes 32-63 hold b_odd; xor-reduce within each 32-lane half.
    float val = acc * W_out[h];
#pragma unroll
    for (int m = 16; m >= 1; m >>= 1)
        val += __shfl_xor(val, m, 64);
    if ((gtid & 31) == 0)
        out[b] = val + b_out[0];
}

extern "C" void kernel_launch(void* const* d_in, const int* in_sizes, int n_in,
                              void* d_out, int out_size, void* d_ws, size_t ws_size,
                              hipStream_t stream)
{
    const float* x     = (const float*)d_in[0];
    const float* Wg    = (const float*)d_in[1];
    const float* tau_m = (const float*)d_in[2];
    const float* soma  = (const float*)d_in[3];
    const float* W_out = (const float*)d_in[4];
    const float* b_out = (const float*)d_in[5];
    float* out = (float*)d_out;

    // 512 blocks x 64 threads = 32768 threads = one (b,h) chain each.
    dim3 grid((BATCH * H) / 64), block(64);
    hipLaunchKernelGGL(snn_fwd, grid, block, 0, stream,
                       x, Wg, tau_m, soma, W_out, b_out, out);
}

// Round 4
// 99.308 us; speedup vs baseline: 1.1039x; 1.1039x over previous
//
#include <hip/hip_runtime.h>

// DelayedXOR SH-SNN forward. One thread per independent (b,h) chain
// (s_g.reshape(B,H) maps (g,j)->h=g*16+j one-to-one; no cross-neuron coupling).
//
// R3 -> R4: dur was invariant (~50us) across 3 register-prefetch structures
// (VGPR 36/52/96) -> global-load vmcnt stalls can't be fixed at source level
// with this compiler. Remove global loads from the loop entirely: stage both
// of the block's x rows (16 KB, contiguous) into LDS once, then the 1024-step
// loop reads via ds_read_b128 (32-lane broadcast, conflict-free). Worst-case
// LDS wait = ~120 cyc per 16-step tile = 7.5 cyc/step, vs ~89 cyc/step of
// stall now. This also discriminates: if dur stays ~50us, the stall is VALU
// dependency latency (in-order wave), and R5 interleaves 2 chains/thread.
//
// Correctness: bit-exact fp32 vs numpy reference (absmax 0.0 in R1-R3).
// - fp contract OFF everywhere (no fma fusion)
// - exact expression order ((ag*v + omg*gi) - sf)
// - spike(v-1) == (v > 1.0f) exactly in fp32
// - (1-alpha)*integ as sf*oms: exact since sf in {0,1}
// - sigmoid in double, rounded once to fp32

constexpr int BATCH = 1024;
constexpr int T     = 1024;
constexpr int H     = 32;
// decision_start = max(T - T/4, T/2) = 768 -> tile 48 of 64 (16 steps/tile)
constexpr int NTILE    = 64;
constexpr int ACC_TILE = 48;

struct XT { float4 q0, q1, q2, q3, q4, q5, q6, q7; };  // 16 timesteps

__device__ __forceinline__ XT lds_tile(const float4* __restrict__ s, int k)
{
    int i = k * 8;
    XT t;
    t.q0 = s[i+0]; t.q1 = s[i+1]; t.q2 = s[i+2]; t.q3 = s[i+3];
    t.q4 = s[i+4]; t.q5 = s[i+5]; t.q6 = s[i+6]; t.q7 = s[i+7];
    return t;
}

template <bool ACC>
__device__ __forceinline__ void step(float x0, float x1,
                                     float w0, float w1,
                                     float ag, float omg,
                                     float as, float oms,
                                     float& v, float& sf,
                                     float& V, float& Sf,
                                     float& acc)
{
#pragma clang fp contract(off)
    float m0 = x0 * w0;          // state-independent: fills latency slots
    float m1 = x1 * w1;
    float gi = m0 + m1;
    float t2 = omg * gi;
    float t1 = ag * v;           // serial core: mul -> add -> sub
    float u  = t1 + t2;
    v = u - sf;
    sf = (v > 1.0f) ? 1.0f : 0.0f;
    float a2 = sf * oms;         // exact for sf in {0,1}
    float a1 = as * V;
    float a3 = a1 + a2;
    V = a3 - Sf;
    Sf = (V > 1.0f) ? 1.0f : 0.0f;
    if (ACC) acc += Sf;
}

template <bool ACC>
__device__ __forceinline__ void tile16(const XT& t,
                                       float w0, float w1,
                                       float ag, float omg,
                                       float as, float oms,
                                       float& v, float& sf,
                                       float& V, float& Sf,
                                       float& acc)
{
#define STEP2(Q) \
    step<ACC>(Q.x, Q.y, w0, w1, ag, omg, as, oms, v, sf, V, Sf, acc); \
    step<ACC>(Q.z, Q.w, w0, w1, ag, omg, as, oms, v, sf, V, Sf, acc);
    STEP2(t.q0) STEP2(t.q1) STEP2(t.q2) STEP2(t.q3)
    STEP2(t.q4) STEP2(t.q5) STEP2(t.q6) STEP2(t.q7)
#undef STEP2
}

__global__ __launch_bounds__(64, 1) void snn_fwd(
    const float* __restrict__ x,       // [B, T, 2]
    const float* __restrict__ Wg,      // [2, 16, 2] == [h][2]
    const float* __restrict__ tau_m,   // [2, 16] == [h]
    const float* __restrict__ soma,    // [32]
    const float* __restrict__ W_out,   // [1, 32]
    const float* __restrict__ b_out,   // [1]
    float* __restrict__ out)           // [B, 1]
{
#pragma clang fp contract(off)
    // Two x rows per block (16 KB). Lanes 0-31: b = 2*blockIdx (sx[0..511]),
    // lanes 32-63: b = 2*blockIdx+1 (sx[512..1023]).
    __shared__ float4 sx[1024];

    const int tid  = threadIdx.x;
    const int h    = tid & (H - 1);
    const int half = tid >> 5;
    const int b    = (blockIdx.x << 1) | half;

    // Cooperative coalesced preload: both rows are contiguous in x.
    const float4* __restrict__ gx =
        (const float4*)(x + (size_t)blockIdx.x * 4096);
#pragma unroll
    for (int k = 0; k < 16; ++k)
        sx[k * 64 + tid] = gx[k * 64 + tid];

    const float w0 = Wg[2*h + 0];
    const float w1 = Wg[2*h + 1];
    const float ag  = (float)(1.0 / (1.0 + exp(-(double)tau_m[h])));
    const float omg = 1.0f - ag;
    const float as  = (float)(1.0 / (1.0 + exp(-(double)soma[h])));
    const float oms = 1.0f - as;

    __syncthreads();

    const float4* sbase = sx + half * 512;   // this thread's row

    float v = 0.f, sf = 0.f, V = 0.f, Sf = 0.f, acc = 0.f;

    // Register double-buffer over 16-step tiles read from LDS.
    XT cur = lds_tile(sbase, 0);

    // phase 1: tiles 0..47, no accumulation
#pragma unroll 2
    for (int k = 0; k < ACC_TILE; ++k) {
        XT nxt = lds_tile(sbase, k + 1);
        tile16<false>(cur, w0, w1, ag, omg, as, oms, v, sf, V, Sf, acc);
        cur = nxt;
    }
    // phase 2: tiles 48..62, accumulate S
#pragma unroll 2
    for (int k = ACC_TILE; k < NTILE - 1; ++k) {
        XT nxt = lds_tile(sbase, k + 1);
        tile16<true>(cur, w0, w1, ag, omg, as, oms, v, sf, V, Sf, acc);
        cur = nxt;
    }
    // tile 63
    tile16<true>(cur, w0, w1, ag, omg, as, oms, v, sf, V, Sf, acc);

    // out[b] = sum_h acc[h] * W_out[h] + b_out. xor-reduce stays within each
    // 32-lane half for m <= 16.
    float val = acc * W_out[h];
#pragma unroll
    for (int m = 16; m >= 1; m >>= 1)
        val += __shfl_xor(val, m, 64);
    if ((tid & 31) == 0)
        out[b] = val + b_out[0];
}

extern "C" void kernel_launch(void* const* d_in, const int* in_sizes, int n_in,
                              void* d_out, int out_size, void* d_ws, size_t ws_size,
                              hipStream_t stream)
{
    const float* x     = (const float*)d_in[0];
    const float* Wg    = (const float*)d_in[1];
    const float* tau_m = (const float*)d_in[2];
    const float* soma  = (const float*)d_in[3];
    const float* W_out = (const float*)d_in[4];
    const float* b_out = (const float*)d_in[5];
    float* out = (float*)d_out;

    // 512 blocks x 64 threads = 32768 threads = one (b,h) chain each.
    dim3 grid((BATCH * H) / 64), block(64);
    hipLaunchKernelGGL(snn_fwd, grid, block, 0, stream,
                       x, Wg, tau_m, soma, W_out, b_out, out);
}